// Round 5
// baseline (132.024 us; speedup 1.0000x reference)
//
#include <hip/hip_runtime.h>
#include <hip/hip_fp16.h>

// ShiftDecoderNet fused kernel for MI355X (gfx950).  R15.
// R5-R10 null: occupancy, VALU -20%, prefetch, barrier count/granularity.
// R11 (112.5->109.6): 2 M-tiles/wave, weight traffic halved.
// R13 FAILED: raw weight loads not line-equivalent to swizzled ws (+26us).
// R14 FAILED (+7us kernel): 4 M-tiles/wave but grid 512 x 4 waves = 2 blk/CU
// -> max 8 waves/CU, measured occ 17% (vs 39.5%). TLP loss ate the reuse
// gain; traffic model not falsified, experiment conflated reuse with waves.
// R15: decouple. 64 rows/block, EIGHT waves (512 thr), grid 512 -> 4096
// waves (== R11), LDS 56.3KB -> 2 blk/CU = 16 waves/CU (== R11). Weight
// frag reuse stays 4x: per-wave weight bytes 48KB (R11) -> 28KB. MFMA/wave
// unchanged (96). Wave w: GEMM1/2 N-eighth (2 nt, ntb=w*2); GEMM3 (w>>2 =
// M-pair, w&3 = nt); Toeplitz 8 rows/wave. 5 barriers (8-wave coupling;
// R10 proved granularity null). Predict occ ~35-40%, kernel ~30us, total
// ~105-107. Flat -> reuse/TLP axis exhausted, write ceiling. >112 -> revert R11.
//
// GEMMs: mfma_f32_16x16x32_bf16.  A-frag: m=lane&15, k=(lane>>4)*8+j.
// C/D: col=lane&15, row=(lane>>4)*4+reg  (verified layouts).

typedef short s8v __attribute__((ext_vector_type(8)));   // 8 bf16 payloads
typedef float f4v __attribute__((ext_vector_type(4)));

#define HPAD 264   // short elements; row stride 528B breaks pow2 bank conflicts
#define PPAD 68    // float elements

// d_ws layout (bf16 elements)
#define OFF_W1F 0        // 16nt x 2kc x 64lane x 8  = 16384
#define OFF_W2F 16384    // 16nt x 8kc x 64lane x 8  = 65536
#define OFF_W3F 81920    //  4nt x 8kc x 64lane x 8  = 16384
#define OFF_B1  98304
#define OFF_G1  98560
#define OFF_BE1 98816
#define OFF_B2  99072
#define OFF_G2  99328
#define OFF_BE2 99584
#define OFF_B3  99840    // 64

__device__ __forceinline__ float b2f(unsigned short u) {
    union { unsigned int i; float f; } v; v.i = ((unsigned int)u) << 16; return v.f;
}
__device__ __forceinline__ unsigned short f2b(float f) {
    union { float f; unsigned int i; } v; v.f = f;
    return (unsigned short)((v.i + 0x7fffu + ((v.i >> 16) & 1u)) >> 16);  // RNE
}
// packed f32x2 -> bf16x2 (lo=a, hi=b), RNE. One VALU inst.
__device__ __forceinline__ unsigned int cvtpk(float a, float b) {
    unsigned int r;
    asm("v_cvt_pk_bf16_f32 %0, %1, %2" : "=v"(r) : "v"(a), "v"(b));
    return r;
}
__device__ __forceinline__ int h2i(__half2 h) { union { __half2 h; int i; } u; u.h = h; return u.i; }
__device__ __forceinline__ __half2 i2h(int i) { union { __half2 h; int i; } u; u.i = i; return u.h; }

__device__ __forceinline__ bool probe_bf16(const void* a_bits) {
    // a_bits is exactly {0.0,1.0}. f32 dwords: {0x0,0x3F800000} (low half 0).
    // packed-bf16 dwords: low half 0x3F80 w.p. 1/2 per word.
    unsigned int wv = ((const unsigned int*)a_bits)[threadIdx.x & 63];
    return __ballot((wv & 0xffffu) == 0x3f80u) != 0ULL;
}

// ============ kernel 0: convert + swizzle weights into d_ws (bf16) ============
__global__ __launch_bounds__(256) void convert_kernel(
    const void* __restrict__ a_probe,
    const void* __restrict__ W1, const void* __restrict__ W2, const void* __restrict__ W3,
    const void* __restrict__ b1, const void* __restrict__ g1, const void* __restrict__ be1,
    const void* __restrict__ b2, const void* __restrict__ g2, const void* __restrict__ be2,
    const void* __restrict__ b3,
    unsigned short* __restrict__ ws)
{
    const bool isbf = probe_bf16(a_probe);
    const int t = blockIdx.x * 256 + threadIdx.x;

    if (t < 12288) {            // weight 8-element chunks, frag order
        const void* W; int K, idx, dstbase;
        if (t < 2048)       { idx = t;         W = W1; K = 64;  dstbase = OFF_W1F + idx * 8; }
        else if (t < 10240) { idx = t - 2048;  W = W2; K = 256; dstbase = OFF_W2F + idx * 8; }
        else                { idx = t - 10240; W = W3; K = 256; dstbase = OFF_W3F + idx * 8; }
        int nt, kc, lane;
        if (t < 2048) { nt = idx >> 7; kc = (idx >> 6) & 1; lane = idx & 63; }
        else          { nt = idx >> 9; kc = (idx >> 6) & 7; lane = idx & 63; }
        const int row = nt * 16 + (lane & 15);
        const int col = kc * 32 + (lane >> 4) * 8;
        const int src = row * K + col;
        s8v o;
        if (isbf) {
            o = *(const s8v*)((const unsigned short*)W + src);
        } else {
            const float* f = (const float*)W + src;
#pragma unroll
            for (int j = 0; j < 8; ++j) o[j] = (short)f2b(f[j]);
        }
        *(s8v*)(ws + dstbase) = o;
    } else if (t < 12488) {     // bias/gamma/beta 8-element chunks
        const int v = t - 12288;
        const void* srcp; int base, off;
        if (v < 32)       { srcp = b1;  base = OFF_B1;  off = v * 8; }
        else if (v < 64)  { srcp = g1;  base = OFF_G1;  off = (v - 32) * 8; }
        else if (v < 96)  { srcp = be1; base = OFF_BE1; off = (v - 64) * 8; }
        else if (v < 128) { srcp = b2;  base = OFF_B2;  off = (v - 96) * 8; }
        else if (v < 160) { srcp = g2;  base = OFF_G2;  off = (v - 128) * 8; }
        else if (v < 192) { srcp = be2; base = OFF_BE2; off = (v - 160) * 8; }
        else              { srcp = b3;  base = OFF_B3;  off = (v - 192) * 8; }
#pragma unroll
        for (int j = 0; j < 8; ++j)
            ws[base + off + j] = isbf ? ((const unsigned short*)srcp)[off + j]
                                      : f2b(((const float*)srcp)[off + j]);
    }
}

// ======================= main fused pipeline ==================================
template<bool BF16>
__device__ __forceinline__ float loadS(const void* p, int idx) {
    if constexpr (BF16) return b2f(((const unsigned short*)p)[idx]);
    else return ((const float*)p)[idx];
}
template<bool BF16>
__device__ __forceinline__ s8v loadA8(const void* p, int idx) {   // activations
    if constexpr (BF16) {
        return *(const s8v*)((const unsigned short*)p + idx);
    } else {
        const float* f = (const float*)p + idx;
        f4v a = *(const f4v*)f;
        f4v b = *(const f4v*)(f + 4);
        union { s8v s; unsigned int u[4]; } r;
        r.u[0] = cvtpk(a[0], a[1]);
        r.u[1] = cvtpk(a[2], a[3]);
        r.u[2] = cvtpk(b[0], b[1]);
        r.u[3] = cvtpk(b[2], b[3]);
        return r.s;
    }
}
template<bool BF16>
__device__ __forceinline__ void storeO(void* p, int idx, float v) {
    if constexpr (BF16) ((unsigned short*)p)[idx] = f2b(v);
    else ((float*)p)[idx] = v;
}

// LN(+bias)+ReLU over acc[8] = [mt*2+i] (mt = M-tile 0..3, i = nt within this
// wave's N-eighth). 8-wave stat exchange: SS is [64 rows][16 floats]
// (8 waves x {sum, sumsq}). Includes the stats barrier.
__device__ __forceinline__ void ln_relu_store(
    f4v* acc, const unsigned short* ws, int offB, int offG, int offBe,
    short* Hs, float* SS, int w, int q, int c, int row, int ntb)
{
    float sm[4][4], sv[4][4];
#pragma unroll
    for (int mt = 0; mt < 4; ++mt)
#pragma unroll
        for (int r = 0; r < 4; ++r) { sm[mt][r] = 0.f; sv[mt][r] = 0.f; }
#pragma unroll
    for (int i = 0; i < 2; ++i) {
        const float bias = b2f(ws[offB + (ntb + i) * 16 + c]);   // shared by all mt
#pragma unroll
        for (int mt = 0; mt < 4; ++mt)
#pragma unroll
            for (int r = 0; r < 4; ++r) {
                float v = acc[mt * 2 + i][r] + bias;
                acc[mt * 2 + i][r] = v;
                sm[mt][r] += v; sv[mt][r] += v * v;
            }
    }
#pragma unroll
    for (int m = 1; m <= 8; m <<= 1)
#pragma unroll
        for (int mt = 0; mt < 4; ++mt)
#pragma unroll
            for (int r = 0; r < 4; ++r) {
                sm[mt][r] += __shfl_xor(sm[mt][r], m, 64);
                sv[mt][r] += __shfl_xor(sv[mt][r], m, 64);
            }
    if (c == 0)
#pragma unroll
        for (int mt = 0; mt < 4; ++mt)
#pragma unroll
            for (int r = 0; r < 4; ++r) {
                const int g = mt * 16 + row + r;
                *(float2*)&SS[g * 16 + w * 2] = make_float2(sm[mt][r], sv[mt][r]);
            }
    __syncthreads();   // stats barrier (bar1 / bar3)
#pragma unroll
    for (int mt = 0; mt < 4; ++mt)
#pragma unroll
        for (int r = 0; r < 4; ++r) {
            const int g = mt * 16 + row + r;
            f4v v0 = *(const f4v*)&SS[g * 16];
            f4v v1 = *(const f4v*)&SS[g * 16 + 4];
            f4v v2 = *(const f4v*)&SS[g * 16 + 8];
            f4v v3 = *(const f4v*)&SS[g * 16 + 12];
            float st = (v0[0] + v0[2]) + (v1[0] + v1[2]) + (v2[0] + v2[2]) + (v3[0] + v3[2]);
            float sq = (v0[1] + v0[3]) + (v1[1] + v1[3]) + (v2[1] + v2[3]) + (v3[1] + v3[3]);
            float mean = st * (1.0f / 256.0f);
            float var  = fmaxf(sq * (1.0f / 256.0f) - mean * mean, 0.0f);
            sm[mt][r] = mean; sv[mt][r] = rsqrtf(var + 1e-5f);
        }
#pragma unroll
    for (int i = 0; i < 2; ++i) {
        const int nt = ntb + i;
        const float gg = b2f(ws[offG + nt * 16 + c]);    // shared by all mt
        const float bb = b2f(ws[offBe + nt * 16 + c]);
#pragma unroll
        for (int mt = 0; mt < 4; ++mt) {
            float y[4];
#pragma unroll
            for (int r = 0; r < 4; ++r)
                y[r] = fmaxf((acc[mt * 2 + i][r] - sm[mt][r]) * sv[mt][r] * gg + bb, 0.0f);
            unsigned int u01 = cvtpk(y[0], y[1]);
            unsigned int u23 = cvtpk(y[2], y[3]);
            Hs[(mt * 16 + row + 0) * HPAD + nt * 16 + c] = (short)(u01 & 0xffffu);
            Hs[(mt * 16 + row + 1) * HPAD + nt * 16 + c] = (short)(u01 >> 16);
            Hs[(mt * 16 + row + 2) * HPAD + nt * 16 + c] = (short)(u23 & 0xffffu);
            Hs[(mt * 16 + row + 3) * HPAD + nt * 16 + c] = (short)(u23 >> 16);
        }
    }
}

template<bool BF16>
__device__ __forceinline__ void pipeline(
    const void* a_bits, const void* shifts, const unsigned short* ws, void* out,
    short* Hs, float* Ps, float* SS, float* SM)
{
    const int tid = threadIdx.x;
    const int w = tid >> 6;        // wave = N-eighth 0..7
    const int l = tid & 63;
    const int q = l >> 4;
    const int c = l & 15;
    const int ntb = w << 1;        // first nt of this wave's eighth (2 nt/wave)
    const int grow0 = (int)blockIdx.x << 6;   // 64 rows/block
    const int row = q * 4;         // +r = this lane's C/D rows (within M-tile)

    // ===== GEMM1: [64x64] @ W1^T -> cols [ntb*16, +32), 4 M-tiles =====
    f4v acc1[8];
#pragma unroll
    for (int i = 0; i < 8; ++i) acc1[i] = (f4v){0.f, 0.f, 0.f, 0.f};

    s8v xa[4][2];
#pragma unroll
    for (int mt = 0; mt < 4; ++mt) {
        xa[mt][0] = loadA8<BF16>(shifts, (grow0 + mt * 16 + c) * 64 + q * 8);
        xa[mt][1] = loadA8<BF16>(shifts, (grow0 + mt * 16 + c) * 64 + 32 + q * 8);
    }
#pragma unroll
    for (int i = 0; i < 2; ++i) {
        const int nt = ntb + i;
        s8v wb0 = *(const s8v*)(ws + OFF_W1F + ((nt * 2 + 0) * 64 + l) * 8);
        s8v wb1 = *(const s8v*)(ws + OFF_W1F + ((nt * 2 + 1) * 64 + l) * 8);
#pragma unroll
        for (int mt = 0; mt < 4; ++mt) {
            acc1[mt * 2 + i] = __builtin_amdgcn_mfma_f32_16x16x32_bf16(xa[mt][0], wb0, acc1[mt * 2 + i], 0, 0, 0);
            acc1[mt * 2 + i] = __builtin_amdgcn_mfma_f32_16x16x32_bf16(xa[mt][1], wb1, acc1[mt * 2 + i], 0, 0, 0);
        }
    }
    ln_relu_store(acc1, ws, OFF_B1, OFF_G1, OFF_BE1, Hs, SS, w, q, c, row, ntb);
    __syncthreads();   // bar2: Hs(v1) ready, SS(LN1) reads done

    // ===== GEMM2: [64x256] @ W2^T -> each weight frag used by 4 M-tiles =====
    f4v acc2[8];
#pragma unroll
    for (int i = 0; i < 8; ++i) acc2[i] = (f4v){0.f, 0.f, 0.f, 0.f};
#pragma unroll
    for (int ks = 0; ks < 8; ++ks) {
        s8v af[4];
#pragma unroll
        for (int mt = 0; mt < 4; ++mt)
            af[mt] = *(const s8v*)&Hs[(mt * 16 + c) * HPAD + ks * 32 + q * 8];
#pragma unroll
        for (int i = 0; i < 2; ++i) {
            s8v bf_ = *(const s8v*)(ws + OFF_W2F + (((ntb + i) * 8 + ks) * 64 + l) * 8);
#pragma unroll
            for (int mt = 0; mt < 4; ++mt)
                acc2[mt * 2 + i] = __builtin_amdgcn_mfma_f32_16x16x32_bf16(af[mt], bf_, acc2[mt * 2 + i], 0, 0, 0);
        }
    }
    ln_relu_store(acc2, ws, OFF_B2, OFF_G2, OFF_BE2, Hs, SS, w, q, c, row, ntb);
    __syncthreads();   // bar4: Hs(v2) ready, SS(LN2) reads done

    // ===== GEMM3: wave w -> M-pair p = w>>2 (mt = p*2+t), nt3 = w&3 =====
    const int nt3 = w & 3;
    const int p = w >> 2;
    f4v acc3[2];
#pragma unroll
    for (int t = 0; t < 2; ++t) acc3[t] = (f4v){0.f, 0.f, 0.f, 0.f};
#pragma unroll
    for (int ks = 0; ks < 8; ++ks) {
        s8v bf_ = *(const s8v*)(ws + OFF_W3F + ((nt3 * 8 + ks) * 64 + l) * 8);
#pragma unroll
        for (int t = 0; t < 2; ++t) {
            s8v af = *(const s8v*)&Hs[((p * 2 + t) * 16 + c) * HPAD + ks * 32 + q * 8];
            acc3[t] = __builtin_amdgcn_mfma_f32_16x16x32_bf16(af, bf_, acc3[t], 0, 0, 0);
        }
    }
    {
        // No max-subtraction (logits bounded, exp-safe). Unnormalized e -> Ps;
        // per-row 16-col partial sums -> SM[g*4 + nt3].
        const float bias = b2f(ws[OFF_B3 + nt3 * 16 + c]);
        float sum[2][4];
#pragma unroll
        for (int t = 0; t < 2; ++t)
#pragma unroll
            for (int r = 0; r < 4; ++r) {
                float e = __expf(acc3[t][r] + bias);
                const int g = (p * 2 + t) * 16 + row + r;
                Ps[g * PPAD + nt3 * 16 + c] = e;
                sum[t][r] = e;
            }
#pragma unroll
        for (int m = 1; m <= 8; m <<= 1)
#pragma unroll
            for (int t = 0; t < 2; ++t)
#pragma unroll
                for (int r = 0; r < 4; ++r)
                    sum[t][r] += __shfl_xor(sum[t][r], m, 64);
        if (c == 0)
#pragma unroll
            for (int t = 0; t < 2; ++t)
#pragma unroll
                for (int r = 0; r < 4; ++r) {
                    const int g = (p * 2 + t) * 16 + row + r;
                    SM[g * 4 + nt3] = sum[t][r];
                }
    }
    __syncthreads();   // bar5: Ps(e) + partial sums visible

    // ===== Toeplitz: out[m,i] = (1/S_m) * sum_{s<=i} e[m,s]*a[m,i-s] =====
    // 8 rows per wave (2 packed per jj). Normalize during half-pack.
#pragma unroll
    for (int jj = 0; jj < 4; ++jj) {
        const int m0 = w * 8 + jj;
        const int m1 = m0 + 4;
        f4v u0 = *(const f4v*)&SM[m0 * 4];
        f4v u1 = *(const f4v*)&SM[m1 * 4];
        const float i0 = __builtin_amdgcn_rcpf(u0[0] + u0[1] + u0[2] + u0[3]);
        const float i1 = __builtin_amdgcn_rcpf(u1[0] + u1[1] + u1[2] + u1[3]);
        __half2 pph = __floats2half2_rn(Ps[m0 * PPAD + l] * i0,
                                        Ps[m1 * PPAD + l] * i1);
        const int ppi = h2i(pph);
        __half2 aah = __floats2half2_rn(loadS<BF16>(a_bits, (grow0 + m0) * 64 + l),
                                        loadS<BF16>(a_bits, (grow0 + m1) * 64 + l));
        int rr = h2i(aah);
        __half2 acc = __float2half2_rn(0.0f);
#pragma unroll
        for (int s = 0; s < 64; ++s) {
            const int spi = __builtin_amdgcn_readlane(ppi, s);
            acc = __hfma2(i2h(spi), i2h(rr), acc);
            if (s < 63)
                rr = __builtin_amdgcn_update_dpp(0, rr, 0x138, 0xF, 0xF, true); // wave_shr:1
        }
        storeO<BF16>(out, (grow0 + m0) * 64 + l, __low2float(acc));
        storeO<BF16>(out, (grow0 + m1) * 64 + l, __high2float(acc));
    }
}

__global__ __launch_bounds__(512, 4) void shiftdec_kernel(
    const void* __restrict__ a_bits, const void* __restrict__ shifts,
    const unsigned short* __restrict__ ws, void* __restrict__ out)
{
    __shared__ __align__(16) short Hs[64 * HPAD];        // 33792 B
    __shared__ __align__(16) float Ps[64 * PPAD];        // 17408 B
    __shared__ __align__(16) float SSb[64 * 16];         // 4096 B LN stat exchange
    __shared__ __align__(16) float SMb[64 * 4];          // 1024 B softmax sums

    if (probe_bf16(a_bits))
        pipeline<true>(a_bits, shifts, ws, out, Hs, Ps, SSb, SMb);
    else
        pipeline<false>(a_bits, shifts, ws, out, Hs, Ps, SSb, SMb);
}

extern "C" void kernel_launch(void* const* d_in, const int* in_sizes, int n_in,
                              void* d_out, int out_size, void* d_ws, size_t ws_size,
                              hipStream_t stream) {
    const int B = in_sizes[0] / 64;      // rows (32768)
    const int grid = B / 64;             // 64 rows per block -> 512 blocks of 512

    hipLaunchKernelGGL(convert_kernel, dim3(49), dim3(256), 0, stream,
                       d_in[0], d_in[2], d_in[6], d_in[10],
                       d_in[3], d_in[4], d_in[5], d_in[7], d_in[8], d_in[9], d_in[11],
                       (unsigned short*)d_ws);
    hipLaunchKernelGGL(shiftdec_kernel, dim3(grid), dim3(512), 0, stream,
                       d_in[0], d_in[1], (const unsigned short*)d_ws, d_out);
}

// Round 6
// 107.079 us; speedup vs baseline: 1.2330x; 1.2330x over previous
//
#include <hip/hip_runtime.h>
#include <hip/hip_fp16.h>

// ShiftDecoderNet fused kernel for MI355X (gfx950).  R16 == exact R11 restore
// (measured 109.565us). Geometry neighborhood fully mapped, R11 is the optimum:
//   R10 (2 waves, 1 M-tile/wave)            ~40us kernel
//   R11 (4 waves, 2 M-tiles/wave, 26KB LDS) ~31-33us kernel  <-- BEST
//   R13 (R11 minus swizzled weights)         64us (raw frag = 16 scattered
//        half-lines vs 8 full lines; convert_kernel's swizzle worth ~26us)
//   R14 (4 waves, 4 M-tiles, 512 blocks)     45.9us (occ 17%, TLP loss)
//   R15 (8 waves, 4 M-tiles, 512 blocks)     52.8us (bank conflicts x4.9,
//        VMEM->LDS traffic shift onto conflicted Hs pattern)
// R5-R10 null: occupancy 16->32 w/CU, VALU -20%, prefetch, barrier count &
// granularity. Micro-lever arithmetic: bpermute/set-bit Toeplitz = 128
// VALU/row vs 96 current at 50% density (worse); bank-conflict fix <=1us at
// R11's 589K count. Kernel is latency-structure-bound (all pipes <40%); no
// remaining theory predicts >2% of total.
//
// GEMMs: mfma_f32_16x16x32_bf16.  A-frag: m=lane&15, k=(lane>>4)*8+j.
// C/D: col=lane&15, row=(lane>>4)*4+reg  (verified layouts).

typedef short s8v __attribute__((ext_vector_type(8)));   // 8 bf16 payloads
typedef float f4v __attribute__((ext_vector_type(4)));

#define HPAD 264   // short elements; row stride 528B breaks pow2 bank conflicts
#define PPAD 68    // float elements

// d_ws layout (bf16 elements)
#define OFF_W1F 0        // 16nt x 2kc x 64lane x 8  = 16384
#define OFF_W2F 16384    // 16nt x 8kc x 64lane x 8  = 65536
#define OFF_W3F 81920    //  4nt x 8kc x 64lane x 8  = 16384
#define OFF_B1  98304
#define OFF_G1  98560
#define OFF_BE1 98816
#define OFF_B2  99072
#define OFF_G2  99328
#define OFF_BE2 99584
#define OFF_B3  99840    // 64

__device__ __forceinline__ float b2f(unsigned short u) {
    union { unsigned int i; float f; } v; v.i = ((unsigned int)u) << 16; return v.f;
}
__device__ __forceinline__ unsigned short f2b(float f) {
    union { float f; unsigned int i; } v; v.f = f;
    return (unsigned short)((v.i + 0x7fffu + ((v.i >> 16) & 1u)) >> 16);  // RNE
}
// packed f32x2 -> bf16x2 (lo=a, hi=b), RNE. One VALU inst.
__device__ __forceinline__ unsigned int cvtpk(float a, float b) {
    unsigned int r;
    asm("v_cvt_pk_bf16_f32 %0, %1, %2" : "=v"(r) : "v"(a), "v"(b));
    return r;
}
__device__ __forceinline__ int h2i(__half2 h) { union { __half2 h; int i; } u; u.h = h; return u.i; }
__device__ __forceinline__ __half2 i2h(int i) { union { __half2 h; int i; } u; u.i = i; return u.h; }

__device__ __forceinline__ bool probe_bf16(const void* a_bits) {
    // a_bits is exactly {0.0,1.0}. f32 dwords: {0x0,0x3F800000} (low half 0).
    // packed-bf16 dwords: low half 0x3F80 w.p. 1/2 per word.
    unsigned int wv = ((const unsigned int*)a_bits)[threadIdx.x & 63];
    return __ballot((wv & 0xffffu) == 0x3f80u) != 0ULL;
}

// ============ kernel 0: convert + swizzle weights into d_ws (bf16) ============
__global__ __launch_bounds__(256) void convert_kernel(
    const void* __restrict__ a_probe,
    const void* __restrict__ W1, const void* __restrict__ W2, const void* __restrict__ W3,
    const void* __restrict__ b1, const void* __restrict__ g1, const void* __restrict__ be1,
    const void* __restrict__ b2, const void* __restrict__ g2, const void* __restrict__ be2,
    const void* __restrict__ b3,
    unsigned short* __restrict__ ws)
{
    const bool isbf = probe_bf16(a_probe);
    const int t = blockIdx.x * 256 + threadIdx.x;

    if (t < 12288) {            // weight 8-element chunks, frag order
        const void* W; int K, idx, dstbase;
        if (t < 2048)       { idx = t;         W = W1; K = 64;  dstbase = OFF_W1F + idx * 8; }
        else if (t < 10240) { idx = t - 2048;  W = W2; K = 256; dstbase = OFF_W2F + idx * 8; }
        else                { idx = t - 10240; W = W3; K = 256; dstbase = OFF_W3F + idx * 8; }
        int nt, kc, lane;
        if (t < 2048) { nt = idx >> 7; kc = (idx >> 6) & 1; lane = idx & 63; }
        else          { nt = idx >> 9; kc = (idx >> 6) & 7; lane = idx & 63; }
        const int row = nt * 16 + (lane & 15);
        const int col = kc * 32 + (lane >> 4) * 8;
        const int src = row * K + col;
        s8v o;
        if (isbf) {
            o = *(const s8v*)((const unsigned short*)W + src);
        } else {
            const float* f = (const float*)W + src;
#pragma unroll
            for (int j = 0; j < 8; ++j) o[j] = (short)f2b(f[j]);
        }
        *(s8v*)(ws + dstbase) = o;
    } else if (t < 12488) {     // bias/gamma/beta 8-element chunks
        const int v = t - 12288;
        const void* srcp; int base, off;
        if (v < 32)       { srcp = b1;  base = OFF_B1;  off = v * 8; }
        else if (v < 64)  { srcp = g1;  base = OFF_G1;  off = (v - 32) * 8; }
        else if (v < 96)  { srcp = be1; base = OFF_BE1; off = (v - 64) * 8; }
        else if (v < 128) { srcp = b2;  base = OFF_B2;  off = (v - 96) * 8; }
        else if (v < 160) { srcp = g2;  base = OFF_G2;  off = (v - 128) * 8; }
        else if (v < 192) { srcp = be2; base = OFF_BE2; off = (v - 160) * 8; }
        else              { srcp = b3;  base = OFF_B3;  off = (v - 192) * 8; }
#pragma unroll
        for (int j = 0; j < 8; ++j)
            ws[base + off + j] = isbf ? ((const unsigned short*)srcp)[off + j]
                                      : f2b(((const float*)srcp)[off + j]);
    }
}

// ======================= main fused pipeline ==================================
template<bool BF16>
__device__ __forceinline__ float loadS(const void* p, int idx) {
    if constexpr (BF16) return b2f(((const unsigned short*)p)[idx]);
    else return ((const float*)p)[idx];
}
template<bool BF16>
__device__ __forceinline__ s8v loadA8(const void* p, int idx) {   // activations
    if constexpr (BF16) {
        return *(const s8v*)((const unsigned short*)p + idx);
    } else {
        const float* f = (const float*)p + idx;
        f4v a = *(const f4v*)f;
        f4v b = *(const f4v*)(f + 4);
        union { s8v s; unsigned int u[4]; } r;
        r.u[0] = cvtpk(a[0], a[1]);
        r.u[1] = cvtpk(a[2], a[3]);
        r.u[2] = cvtpk(b[0], b[1]);
        r.u[3] = cvtpk(b[2], b[3]);
        return r.s;
    }
}
template<bool BF16>
__device__ __forceinline__ void storeO(void* p, int idx, float v) {
    if constexpr (BF16) ((unsigned short*)p)[idx] = f2b(v);
    else ((float*)p)[idx] = v;
}

// LN(+bias)+ReLU over acc[8] = [mt*4+i] (mt = M-tile 0/1, i = nt within this
// wave's N-quarter). Includes the stats barrier; caller adds the Hs barrier.
__device__ __forceinline__ void ln_relu_store(
    f4v* acc, const unsigned short* ws, int offB, int offG, int offBe,
    short* Hs, float* SS, int w, int q, int c, int row, int ntb)
{
    float sm[2][4], sv[2][4];
#pragma unroll
    for (int mt = 0; mt < 2; ++mt)
#pragma unroll
        for (int r = 0; r < 4; ++r) { sm[mt][r] = 0.f; sv[mt][r] = 0.f; }
#pragma unroll
    for (int i = 0; i < 4; ++i) {
        const float bias = b2f(ws[offB + (ntb + i) * 16 + c]);   // shared by both mt
#pragma unroll
        for (int mt = 0; mt < 2; ++mt)
#pragma unroll
            for (int r = 0; r < 4; ++r) {
                float v = acc[mt * 4 + i][r] + bias;
                acc[mt * 4 + i][r] = v;
                sm[mt][r] += v; sv[mt][r] += v * v;
            }
    }
#pragma unroll
    for (int m = 1; m <= 8; m <<= 1)
#pragma unroll
        for (int mt = 0; mt < 2; ++mt)
#pragma unroll
            for (int r = 0; r < 4; ++r) {
                sm[mt][r] += __shfl_xor(sm[mt][r], m, 64);
                sv[mt][r] += __shfl_xor(sv[mt][r], m, 64);
            }
    if (c == 0)
#pragma unroll
        for (int mt = 0; mt < 2; ++mt)
#pragma unroll
            for (int r = 0; r < 4; ++r) {
                const int g = mt * 16 + row + r;
                *(float2*)&SS[g * 8 + w * 2] = make_float2(sm[mt][r], sv[mt][r]);
            }
    __syncthreads();   // stats barrier (bar1 / bar3)
#pragma unroll
    for (int mt = 0; mt < 2; ++mt)
#pragma unroll
        for (int r = 0; r < 4; ++r) {
            const int g = mt * 16 + row + r;
            f4v v0 = *(const f4v*)&SS[g * 8];
            f4v v1 = *(const f4v*)&SS[g * 8 + 4];
            float st = v0[0] + v0[2] + v1[0] + v1[2];
            float sq = v0[1] + v0[3] + v1[1] + v1[3];
            float mean = st * (1.0f / 256.0f);
            float var  = fmaxf(sq * (1.0f / 256.0f) - mean * mean, 0.0f);
            sm[mt][r] = mean; sv[mt][r] = rsqrtf(var + 1e-5f);
        }
#pragma unroll
    for (int i = 0; i < 4; ++i) {
        const int nt = ntb + i;
        const float gg = b2f(ws[offG + nt * 16 + c]);    // shared by both mt
        const float bb = b2f(ws[offBe + nt * 16 + c]);
#pragma unroll
        for (int mt = 0; mt < 2; ++mt) {
            float y[4];
#pragma unroll
            for (int r = 0; r < 4; ++r)
                y[r] = fmaxf((acc[mt * 4 + i][r] - sm[mt][r]) * sv[mt][r] * gg + bb, 0.0f);
            unsigned int u01 = cvtpk(y[0], y[1]);
            unsigned int u23 = cvtpk(y[2], y[3]);
            Hs[(mt * 16 + row + 0) * HPAD + nt * 16 + c] = (short)(u01 & 0xffffu);
            Hs[(mt * 16 + row + 1) * HPAD + nt * 16 + c] = (short)(u01 >> 16);
            Hs[(mt * 16 + row + 2) * HPAD + nt * 16 + c] = (short)(u23 & 0xffffu);
            Hs[(mt * 16 + row + 3) * HPAD + nt * 16 + c] = (short)(u23 >> 16);
        }
    }
}

template<bool BF16>
__device__ __forceinline__ void pipeline(
    const void* a_bits, const void* shifts, const unsigned short* ws, void* out,
    short* Hs, float* Ps, float* SS)
{
    const int tid = threadIdx.x;
    const int w = tid >> 6;        // wave = N-quarter 0..3
    const int l = tid & 63;
    const int q = l >> 4;
    const int c = l & 15;
    const int ntb = w << 2;        // first nt of this wave's quarter
    const int grow0 = (int)blockIdx.x << 5;   // 32 rows/block
    const int row = q * 4;         // +r = this lane's C/D rows (within M-tile)

    // ===== GEMM1: [32x64] @ W1^T -> cols [ntb*16, +64), 2 M-tiles =====
    f4v acc1[8];
#pragma unroll
    for (int i = 0; i < 8; ++i) acc1[i] = (f4v){0.f, 0.f, 0.f, 0.f};

    const s8v xa00 = loadA8<BF16>(shifts, (grow0 + c) * 64 + q * 8);
    const s8v xa01 = loadA8<BF16>(shifts, (grow0 + c) * 64 + 32 + q * 8);
    const s8v xa10 = loadA8<BF16>(shifts, (grow0 + 16 + c) * 64 + q * 8);
    const s8v xa11 = loadA8<BF16>(shifts, (grow0 + 16 + c) * 64 + 32 + q * 8);
#pragma unroll
    for (int i = 0; i < 4; ++i) {
        const int nt = ntb + i;
        s8v wb0 = *(const s8v*)(ws + OFF_W1F + ((nt * 2 + 0) * 64 + l) * 8);
        s8v wb1 = *(const s8v*)(ws + OFF_W1F + ((nt * 2 + 1) * 64 + l) * 8);
        acc1[i]     = __builtin_amdgcn_mfma_f32_16x16x32_bf16(xa00, wb0, acc1[i], 0, 0, 0);
        acc1[i]     = __builtin_amdgcn_mfma_f32_16x16x32_bf16(xa01, wb1, acc1[i], 0, 0, 0);
        acc1[4 + i] = __builtin_amdgcn_mfma_f32_16x16x32_bf16(xa10, wb0, acc1[4 + i], 0, 0, 0);
        acc1[4 + i] = __builtin_amdgcn_mfma_f32_16x16x32_bf16(xa11, wb1, acc1[4 + i], 0, 0, 0);
    }
    ln_relu_store(acc1, ws, OFF_B1, OFF_G1, OFF_BE1, Hs, SS, w, q, c, row, ntb);
    __syncthreads();   // bar2: Hs(v1) ready, SS(LN1) reads done

    // ===== GEMM2: [32x256] @ W2^T -> each weight frag used by 2 M-tiles =====
    f4v acc2[8];
#pragma unroll
    for (int i = 0; i < 8; ++i) acc2[i] = (f4v){0.f, 0.f, 0.f, 0.f};
#pragma unroll
    for (int ks = 0; ks < 8; ++ks) {
        s8v af0 = *(const s8v*)&Hs[c * HPAD + ks * 32 + q * 8];
        s8v af1 = *(const s8v*)&Hs[(16 + c) * HPAD + ks * 32 + q * 8];
#pragma unroll
        for (int i = 0; i < 4; ++i) {
            s8v bf_ = *(const s8v*)(ws + OFF_W2F + (((ntb + i) * 8 + ks) * 64 + l) * 8);
            acc2[i]     = __builtin_amdgcn_mfma_f32_16x16x32_bf16(af0, bf_, acc2[i], 0, 0, 0);
            acc2[4 + i] = __builtin_amdgcn_mfma_f32_16x16x32_bf16(af1, bf_, acc2[4 + i], 0, 0, 0);
        }
    }
    ln_relu_store(acc2, ws, OFF_B2, OFF_G2, OFF_BE2, Hs, SS, w, q, c, row, ntb);
    __syncthreads();   // bar4: Hs(v2) ready, SS(LN2) reads done

    // ===== GEMM3: wave w computes cols [w*16, +16) for both M-tiles =====
    f4v acc3[2];
#pragma unroll
    for (int t = 0; t < 2; ++t) acc3[t] = (f4v){0.f, 0.f, 0.f, 0.f};
#pragma unroll
    for (int ks = 0; ks < 8; ++ks) {
        s8v af0 = *(const s8v*)&Hs[c * HPAD + ks * 32 + q * 8];
        s8v af1 = *(const s8v*)&Hs[(16 + c) * HPAD + ks * 32 + q * 8];
        // W3 frag: nt = w (wave's 16 cols)
        s8v bf_ = *(const s8v*)(ws + OFF_W3F + ((w * 8 + ks) * 64 + l) * 8);
        acc3[0] = __builtin_amdgcn_mfma_f32_16x16x32_bf16(af0, bf_, acc3[0], 0, 0, 0);
        acc3[1] = __builtin_amdgcn_mfma_f32_16x16x32_bf16(af1, bf_, acc3[1], 0, 0, 0);
    }
    {
        // No max-subtraction (logits bounded, exp-safe). Unnormalized e -> Ps;
        // per-row partial sums (this wave's 16 cols) -> SS odd slots.
        const float bias = b2f(ws[OFF_B3 + w * 16 + c]);
        float sum[2][4];
#pragma unroll
        for (int mt = 0; mt < 2; ++mt)
#pragma unroll
            for (int r = 0; r < 4; ++r) {
                float e = __expf(acc3[mt][r] + bias);
                Ps[(mt * 16 + row + r) * PPAD + w * 16 + c] = e;
                sum[mt][r] = e;
            }
#pragma unroll
        for (int m = 1; m <= 8; m <<= 1)
#pragma unroll
            for (int mt = 0; mt < 2; ++mt)
#pragma unroll
                for (int r = 0; r < 4; ++r)
                    sum[mt][r] += __shfl_xor(sum[mt][r], m, 64);
        if (c == 0)
#pragma unroll
            for (int mt = 0; mt < 2; ++mt)
#pragma unroll
                for (int r = 0; r < 4; ++r)
                    SS[(mt * 16 + row + r) * 8 + w * 2 + 1] = sum[mt][r];
    }
    __syncthreads();   // bar5: Ps(e) + partial sums visible

    // ===== Toeplitz: out[m,i] = (1/S_m) * sum_{s<=i} e[m,s]*a[m,i-s] =====
    // 8 rows per wave (2 packed per jj). Normalize during half-pack.
#pragma unroll
    for (int jj = 0; jj < 4; ++jj) {
        const int m0 = w * 8 + jj;
        const int m1 = m0 + 4;
        f4v u0 = *(const f4v*)&SS[m0 * 8];
        f4v u1 = *(const f4v*)&SS[m0 * 8 + 4];
        f4v u2 = *(const f4v*)&SS[m1 * 8];
        f4v u3 = *(const f4v*)&SS[m1 * 8 + 4];
        const float i0 = __builtin_amdgcn_rcpf(u0[1] + u0[3] + u1[1] + u1[3]);
        const float i1 = __builtin_amdgcn_rcpf(u2[1] + u2[3] + u3[1] + u3[3]);
        __half2 pph = __floats2half2_rn(Ps[m0 * PPAD + l] * i0,
                                        Ps[m1 * PPAD + l] * i1);
        const int ppi = h2i(pph);
        __half2 aah = __floats2half2_rn(loadS<BF16>(a_bits, (grow0 + m0) * 64 + l),
                                        loadS<BF16>(a_bits, (grow0 + m1) * 64 + l));
        int rr = h2i(aah);
        __half2 acc = __float2half2_rn(0.0f);
#pragma unroll
        for (int s = 0; s < 64; ++s) {
            const int spi = __builtin_amdgcn_readlane(ppi, s);
            acc = __hfma2(i2h(spi), i2h(rr), acc);
            if (s < 63)
                rr = __builtin_amdgcn_update_dpp(0, rr, 0x138, 0xF, 0xF, true); // wave_shr:1
        }
        storeO<BF16>(out, (grow0 + m0) * 64 + l, __low2float(acc));
        storeO<BF16>(out, (grow0 + m1) * 64 + l, __high2float(acc));
    }
}

__global__ __launch_bounds__(256, 4) void shiftdec_kernel(
    const void* __restrict__ a_bits, const void* __restrict__ shifts,
    const unsigned short* __restrict__ ws, void* __restrict__ out)
{
    __shared__ __align__(16) short Hs[32 * HPAD];        // 16896 B
    __shared__ __align__(16) float Ps[32 * PPAD];        // 8704 B
    __shared__ __align__(16) float SSb[32 * 8];          // 1024 B stat exchange

    if (probe_bf16(a_bits))
        pipeline<true>(a_bits, shifts, ws, out, Hs, Ps, SSb);
    else
        pipeline<false>(a_bits, shifts, ws, out, Hs, Ps, SSb);
}

extern "C" void kernel_launch(void* const* d_in, const int* in_sizes, int n_in,
                              void* d_out, int out_size, void* d_ws, size_t ws_size,
                              hipStream_t stream) {
    const int B = in_sizes[0] / 64;      // rows (32768)
    const int grid = B / 32;             // 32 rows per block -> 1024 blocks of 256

    hipLaunchKernelGGL(convert_kernel, dim3(49), dim3(256), 0, stream,
                       d_in[0], d_in[2], d_in[6], d_in[10],
                       d_in[3], d_in[4], d_in[5], d_in[7], d_in[8], d_in[9], d_in[11],
                       (unsigned short*)d_ws);
    hipLaunchKernelGGL(shiftdec_kernel, dim3(grid), dim3(256), 0, stream,
                       d_in[0], d_in[1], (const unsigned short*)d_ws, d_out);
}